// Round 1
// baseline (2497.695 us; speedup 1.0000x reference)
//
#include <hip/hip_runtime.h>
#include <math.h>

#define N_NODES 50000
#define N_EDGES 800000

// ---------------------------------------------------------------------------
// GEMM1: C[M,128] = A[M,500] @ B[500,128], fp32.
// BM=64 rows/block, BK=20 (500 = 25*20), BN=128 (full width).
// Thread layout: 32 col-groups (TN=4) x 8 row-groups (TM=8) = 256 threads.
// ---------------------------------------------------------------------------
__global__ __launch_bounds__(256) void gemm1_kernel(
    const float* __restrict__ A, const float* __restrict__ B,
    float* __restrict__ C)
{
    constexpr int K = 500, N = 128, BM = 64, BK = 20;
    constexpr int PAD = BM + 4;   // bank-conflict pad for column-major As writes
    __shared__ float As[BK * PAD];
    __shared__ float Bs[BK * N];

    const int t = threadIdx.x;
    const int row0 = blockIdx.x * BM;
    const int tx = t & 31;   // col group: cols tx*4 .. tx*4+3
    const int ty = t >> 5;   // row group: rows ty*8 .. ty*8+7

    float acc[8][4] = {};

    for (int k0 = 0; k0 < K; k0 += BK) {
        // A tile: 64x20 = 1280 elems, 5 per thread
#pragma unroll
        for (int i = 0; i < 5; ++i) {
            int idx = t + i * 256;
            int kk = idx % BK, m = idx / BK;
            int gr = row0 + m;
            float v = (gr < N_NODES) ? A[(size_t)gr * K + k0 + kk] : 0.0f;
            As[kk * PAD + m] = v;
        }
        // B tile: 20x128 = 2560 elems, 10 per thread (fully coalesced)
#pragma unroll
        for (int i = 0; i < 10; ++i) {
            int idx = t + i * 256;
            int kr = idx >> 7, n = idx & 127;
            Bs[kr * N + n] = B[(size_t)(k0 + kr) * N + n];
        }
        __syncthreads();
#pragma unroll
        for (int kk = 0; kk < BK; ++kk) {
            float a[8], b[4];
#pragma unroll
            for (int i = 0; i < 8; ++i) a[i] = As[kk * PAD + ty * 8 + i];
#pragma unroll
            for (int j = 0; j < 4; ++j) b[j] = Bs[kk * N + tx * 4 + j];
#pragma unroll
            for (int i = 0; i < 8; ++i)
#pragma unroll
                for (int j = 0; j < 4; ++j) acc[i][j] += a[i] * b[j];
        }
        __syncthreads();
    }

#pragma unroll
    for (int i = 0; i < 8; ++i) {
        int gr = row0 + ty * 8 + i;
        if (gr < N_NODES) {
            float4 v = make_float4(acc[i][0], acc[i][1], acc[i][2], acc[i][3]);
            *reinterpret_cast<float4*>(C + (size_t)gr * N + tx * 4) = v;
        }
    }
}

// ---------------------------------------------------------------------------
// Small-K GEMM: C[M,N] = f(A[M,K]) @ B[K,N] (+ bC), with optional
// f(a) = relu(a + bA[k]) applied on the fly to A (fuses relu+bias of the
// previous GCN layer). B is resident in LDS (K*N*4 <= 32 KB).
// ---------------------------------------------------------------------------
template <int K, int N, int TM, int TN, bool RELU_A, bool BIAS_C>
__global__ __launch_bounds__(256) void gemm_small_kernel(
    const float* __restrict__ A, const float* __restrict__ B,
    const float* __restrict__ bA, const float* __restrict__ bC,
    float* __restrict__ C, int M)
{
    constexpr int BM = 64;
    constexpr int BK = 32;
    constexpr int PAD = BM + 4;
    constexpr int RG = BM / TM;
    constexpr int CG = N / TN;
    static_assert(RG * CG == 256, "thread layout");
    static_assert(K % BK == 0, "K chunking");

    __shared__ float Bs[K * N];
    __shared__ float As[BK * PAD];

    const int t = threadIdx.x;
    const int row0 = blockIdx.x * BM;
    const int tx = t % CG;
    const int ty = t / CG;

    constexpr int BLOADS = (K * N) / 256;
#pragma unroll
    for (int i = 0; i < BLOADS; ++i) {
        int idx = t + i * 256;
        Bs[idx] = B[idx];
    }

    float acc[TM][TN] = {};

    for (int k0 = 0; k0 < K; k0 += BK) {
        float av[(BK * BM) / 256];
#pragma unroll
        for (int i = 0; i < (BK * BM) / 256; ++i) {
            int idx = t + i * 256;
            int kk = idx % BK, m = idx / BK;
            int gr = row0 + m;
            float v = (gr < M) ? A[(size_t)gr * K + k0 + kk] : 0.0f;
            if constexpr (RELU_A) {
                v += bA[k0 + kk];
                v = v > 0.0f ? v : 0.0f;
            }
            av[i] = v;
        }
        __syncthreads();   // prev compute done (and Bs visible on iter 0)
#pragma unroll
        for (int i = 0; i < (BK * BM) / 256; ++i) {
            int idx = t + i * 256;
            As[(idx % BK) * PAD + idx / BK] = av[i];
        }
        __syncthreads();
#pragma unroll
        for (int kk = 0; kk < BK; ++kk) {
            float a[TM], b[TN];
#pragma unroll
            for (int i = 0; i < TM; ++i) a[i] = As[kk * PAD + ty * TM + i];
#pragma unroll
            for (int j = 0; j < TN; ++j) b[j] = Bs[(k0 + kk) * N + tx * TN + j];
#pragma unroll
            for (int i = 0; i < TM; ++i)
#pragma unroll
                for (int j = 0; j < TN; ++j) acc[i][j] += a[i] * b[j];
        }
    }

#pragma unroll
    for (int i = 0; i < TM; ++i) {
        int gr = row0 + ty * TM + i;
        if (gr < M) {
            if constexpr (TN == 4) {
                float4 v;
                v.x = acc[i][0]; v.y = acc[i][1]; v.z = acc[i][2]; v.w = acc[i][3];
                if constexpr (BIAS_C) {
                    v.x += bC[tx * 4 + 0]; v.y += bC[tx * 4 + 1];
                    v.z += bC[tx * 4 + 2]; v.w += bC[tx * 4 + 3];
                }
                *reinterpret_cast<float4*>(C + (size_t)gr * N + tx * 4) = v;
            } else {
#pragma unroll
                for (int j = 0; j < TN; ++j) {
                    float v = acc[i][j];
                    if constexpr (BIAS_C) v += bC[tx * TN + j];
                    C[(size_t)gr * N + tx * TN + j] = v;
                }
            }
        }
    }
}

// ---------------------------------------------------------------------------
// Edge scatter: agg[src[e], :] += support[dst[e], :] * vals[e]
// F/4 threads per edge, float4 gather + 4 scalar float atomics.
// ---------------------------------------------------------------------------
template <int F>
__global__ __launch_bounds__(256) void scatter_kernel(
    const float* __restrict__ support, const float* __restrict__ vals,
    const int* __restrict__ src, const int* __restrict__ dst,
    float* __restrict__ agg)
{
    constexpr int TPE = F / 4;
    size_t gid = (size_t)blockIdx.x * 256 + threadIdx.x;
    int e = (int)(gid / TPE);
    if (e >= N_EDGES) return;
    int f = (int)(gid % TPE) * 4;
    float v = vals[e];
    int d = dst[e], s = src[e];
    const float4 m = *reinterpret_cast<const float4*>(support + (size_t)d * F + f);
    float* out = agg + (size_t)s * F + f;
    atomicAdd(out + 0, m.x * v);
    atomicAdd(out + 1, m.y * v);
    atomicAdd(out + 2, m.z * v);
    atomicAdd(out + 3, m.w * v);
}

// ---------------------------------------------------------------------------
// Row-wise log_softmax over 16 columns (with bias b3): out = v - (max + log(sum exp))
// ---------------------------------------------------------------------------
__global__ __launch_bounds__(256) void logsoftmax_kernel(
    const float* __restrict__ agg, const float* __restrict__ b3,
    float* __restrict__ out)
{
    int row = blockIdx.x * 256 + threadIdx.x;
    if (row >= N_NODES) return;
    float v[16];
    const float4* p = reinterpret_cast<const float4*>(agg + (size_t)row * 16);
#pragma unroll
    for (int i = 0; i < 4; ++i) {
        float4 q = p[i];
        v[i * 4 + 0] = q.x + b3[i * 4 + 0];
        v[i * 4 + 1] = q.y + b3[i * 4 + 1];
        v[i * 4 + 2] = q.z + b3[i * 4 + 2];
        v[i * 4 + 3] = q.w + b3[i * 4 + 3];
    }
    float mx = v[0];
#pragma unroll
    for (int i = 1; i < 16; ++i) mx = fmaxf(mx, v[i]);
    float s = 0.0f;
#pragma unroll
    for (int i = 0; i < 16; ++i) s += expf(v[i] - mx);
    float lse = mx + logf(s);
    float4* o = reinterpret_cast<float4*>(out + (size_t)row * 16);
#pragma unroll
    for (int i = 0; i < 4; ++i)
        o[i] = make_float4(v[i * 4 + 0] - lse, v[i * 4 + 1] - lse,
                           v[i * 4 + 2] - lse, v[i * 4 + 3] - lse);
}

// ---------------------------------------------------------------------------
extern "C" void kernel_launch(void* const* d_in, const int* in_sizes, int n_in,
                              void* d_out, int out_size, void* d_ws, size_t ws_size,
                              hipStream_t stream)
{
    const float* x         = (const float*)d_in[0];   // [50000,500]
    const float* edge_vals = (const float*)d_in[1];   // [800000]
    const float* W1 = (const float*)d_in[2];          // [500,128]
    const float* b1 = (const float*)d_in[3];          // [128]
    const float* W2 = (const float*)d_in[4];          // [128,64]
    const float* b2 = (const float*)d_in[5];          // [64]
    const float* W3 = (const float*)d_in[6];          // [64,16]
    const float* b3 = (const float*)d_in[7];          // [16]
    const float* We = (const float*)d_in[8];          // [64,64]
    const float* be = (const float*)d_in[9];          // [64]
    const int* esrc = (const int*)d_in[10];           // [800000]
    const int* edst = (const int*)d_in[11];           // [800000]

    float* out1 = (float*)d_out;                           // [50000,16]
    float* out2 = (float*)d_out + (size_t)N_NODES * 16;    // [50000,64]

    char* ws = (char*)d_ws;
    float* bufA = (float*)(ws);                 // 25,600,000 B
    float* bufB = (float*)(ws + 25600000);      // 25,600,000 B
    float* bufC = (float*)(ws + 51200000);      //  3,200,000 B

    const int MB = (N_NODES + 63) / 64;  // 782 row blocks

    // 1. support1 = x @ W1                                  -> bufA [N,128]
    gemm1_kernel<<<MB, 256, 0, stream>>>(x, W1, bufA);

    // 2. agg1 = segment_sum(support1[dst]*val, src)         -> bufB [N,128]
    hipMemsetAsync(bufB, 0, (size_t)N_NODES * 128 * 4, stream);
    scatter_kernel<128><<<(N_EDGES * 32) / 256, 256, 0, stream>>>(
        bufA, edge_vals, esrc, edst, bufB);

    // 3. support2 = relu(agg1 + b1) @ W2                    -> bufA [N,64]
    gemm_small_kernel<128, 64, 4, 4, true, false><<<MB, 256, 0, stream>>>(
        bufB, W2, b1, nullptr, bufA, N_NODES);

    // 4. agg2                                               -> bufB [N,64]
    hipMemsetAsync(bufB, 0, (size_t)N_NODES * 64 * 4, stream);
    scatter_kernel<64><<<(N_EDGES * 16) / 256, 256, 0, stream>>>(
        bufA, edge_vals, esrc, edst, bufB);

    // 5. out2 = relu(agg2 + b2) @ We + be                   -> d_out tail
    gemm_small_kernel<64, 64, 4, 4, true, true><<<MB, 256, 0, stream>>>(
        bufB, We, b2, be, out2, N_NODES);

    // 6. support3 = relu(agg2 + b2) @ W3                    -> bufA [N,16]
    gemm_small_kernel<64, 16, 4, 1, true, false><<<MB, 256, 0, stream>>>(
        bufB, W3, b2, nullptr, bufA, N_NODES);

    // 7. agg3                                               -> bufC [N,16]
    hipMemsetAsync(bufC, 0, (size_t)N_NODES * 16 * 4, stream);
    scatter_kernel<16><<<(N_EDGES * 4) / 256, 256, 0, stream>>>(
        bufA, edge_vals, esrc, edst, bufC);

    // 8. out1 = log_softmax(agg3 + b3)                      -> d_out head
    logsoftmax_kernel<<<(N_NODES + 255) / 256, 256, 0, stream>>>(bufC, b3, out1);
}

// Round 2
// 855.683 us; speedup vs baseline: 2.9189x; 2.9189x over previous
//
#include <hip/hip_runtime.h>
#include <math.h>

#define N_NODES 50000
#define N_EDGES 800000

// ---------------------------------------------------------------------------
// GEMM1: C[M,128] = A[M,500] @ B[500,128], fp32.
// ---------------------------------------------------------------------------
__global__ __launch_bounds__(256) void gemm1_kernel(
    const float* __restrict__ A, const float* __restrict__ B,
    float* __restrict__ C)
{
    constexpr int K = 500, N = 128, BM = 64, BK = 20;
    constexpr int PAD = BM + 4;
    __shared__ float As[BK * PAD];
    __shared__ float Bs[BK * N];

    const int t = threadIdx.x;
    const int row0 = blockIdx.x * BM;
    const int tx = t & 31;
    const int ty = t >> 5;

    float acc[8][4] = {};

    for (int k0 = 0; k0 < K; k0 += BK) {
#pragma unroll
        for (int i = 0; i < 5; ++i) {
            int idx = t + i * 256;
            int kk = idx % BK, m = idx / BK;
            int gr = row0 + m;
            float v = (gr < N_NODES) ? A[(size_t)gr * K + k0 + kk] : 0.0f;
            As[kk * PAD + m] = v;
        }
#pragma unroll
        for (int i = 0; i < 10; ++i) {
            int idx = t + i * 256;
            int kr = idx >> 7, n = idx & 127;
            Bs[kr * N + n] = B[(size_t)(k0 + kr) * N + n];
        }
        __syncthreads();
#pragma unroll
        for (int kk = 0; kk < BK; ++kk) {
            float a[8], b[4];
#pragma unroll
            for (int i = 0; i < 8; ++i) a[i] = As[kk * PAD + ty * 8 + i];
#pragma unroll
            for (int j = 0; j < 4; ++j) b[j] = Bs[kk * N + tx * 4 + j];
#pragma unroll
            for (int i = 0; i < 8; ++i)
#pragma unroll
                for (int j = 0; j < 4; ++j) acc[i][j] += a[i] * b[j];
        }
        __syncthreads();
    }

#pragma unroll
    for (int i = 0; i < 8; ++i) {
        int gr = row0 + ty * 8 + i;
        if (gr < N_NODES) {
            float4 v = make_float4(acc[i][0], acc[i][1], acc[i][2], acc[i][3]);
            *reinterpret_cast<float4*>(C + (size_t)gr * N + tx * 4) = v;
        }
    }
}

// ---------------------------------------------------------------------------
// Small-K GEMM: C[M,N] = f(A[M,K]) @ B[K,N] (+ bC), f = relu(a + bA[k]).
// ---------------------------------------------------------------------------
template <int K, int N, int TM, int TN, bool RELU_A, bool BIAS_C>
__global__ __launch_bounds__(256) void gemm_small_kernel(
    const float* __restrict__ A, const float* __restrict__ B,
    const float* __restrict__ bA, const float* __restrict__ bC,
    float* __restrict__ C, int M)
{
    constexpr int BM = 64;
    constexpr int BK = 32;
    constexpr int PAD = BM + 4;
    constexpr int RG = BM / TM;
    constexpr int CG = N / TN;
    static_assert(RG * CG == 256, "thread layout");
    static_assert(K % BK == 0, "K chunking");

    __shared__ float Bs[K * N];
    __shared__ float As[BK * PAD];

    const int t = threadIdx.x;
    const int row0 = blockIdx.x * BM;
    const int tx = t % CG;
    const int ty = t / CG;

    constexpr int BLOADS = (K * N) / 256;
#pragma unroll
    for (int i = 0; i < BLOADS; ++i) {
        int idx = t + i * 256;
        Bs[idx] = B[idx];
    }

    float acc[TM][TN] = {};

    for (int k0 = 0; k0 < K; k0 += BK) {
        float av[(BK * BM) / 256];
#pragma unroll
        for (int i = 0; i < (BK * BM) / 256; ++i) {
            int idx = t + i * 256;
            int kk = idx % BK, m = idx / BK;
            int gr = row0 + m;
            float v = (gr < M) ? A[(size_t)gr * K + k0 + kk] : 0.0f;
            if constexpr (RELU_A) {
                v += bA[k0 + kk];
                v = v > 0.0f ? v : 0.0f;
            }
            av[i] = v;
        }
        __syncthreads();
#pragma unroll
        for (int i = 0; i < (BK * BM) / 256; ++i) {
            int idx = t + i * 256;
            As[(idx % BK) * PAD + idx / BK] = av[i];
        }
        __syncthreads();
#pragma unroll
        for (int kk = 0; kk < BK; ++kk) {
            float a[TM], b[TN];
#pragma unroll
            for (int i = 0; i < TM; ++i) a[i] = As[kk * PAD + ty * TM + i];
#pragma unroll
            for (int j = 0; j < TN; ++j) b[j] = Bs[(k0 + kk) * N + tx * TN + j];
#pragma unroll
            for (int i = 0; i < TM; ++i)
#pragma unroll
                for (int j = 0; j < TN; ++j) acc[i][j] += a[i] * b[j];
        }
    }

#pragma unroll
    for (int i = 0; i < TM; ++i) {
        int gr = row0 + ty * TM + i;
        if (gr < M) {
            if constexpr (TN == 4) {
                float4 v;
                v.x = acc[i][0]; v.y = acc[i][1]; v.z = acc[i][2]; v.w = acc[i][3];
                if constexpr (BIAS_C) {
                    v.x += bC[tx * 4 + 0]; v.y += bC[tx * 4 + 1];
                    v.z += bC[tx * 4 + 2]; v.w += bC[tx * 4 + 3];
                }
                *reinterpret_cast<float4*>(C + (size_t)gr * N + tx * 4) = v;
            } else {
#pragma unroll
                for (int j = 0; j < TN; ++j) {
                    float v = acc[i][j];
                    if constexpr (BIAS_C) v += bC[tx * TN + j];
                    C[(size_t)gr * N + tx * TN + j] = v;
                }
            }
        }
    }
}

// ---------------------------------------------------------------------------
// CSR build (per launch; reused by all 3 aggregation layers).
// ---------------------------------------------------------------------------
__global__ __launch_bounds__(256) void hist_kernel(
    const int* __restrict__ src, int* __restrict__ counts)
{
    int e = blockIdx.x * 256 + threadIdx.x;
    if (e < N_EDGES) atomicAdd(&counts[src[e]], 1);
}

// Single wave, barrier-free exclusive scan of counts -> row_ptr (+cursor copy).
__global__ __launch_bounds__(64) void scan_kernel(
    const int* __restrict__ counts, int* __restrict__ row_ptr,
    int* __restrict__ cursor)
{
    int lane = threadIdx.x;
    int carry = 0;
    for (int base = 0; base < N_NODES; base += 64) {
        int idx = base + lane;
        int v = (idx < N_NODES) ? counts[idx] : 0;
        int incl = v;
#pragma unroll
        for (int off = 1; off < 64; off <<= 1) {
            int n = __shfl_up(incl, off, 64);
            if (lane >= off) incl += n;
        }
        int excl = incl - v;
        if (idx < N_NODES) {
            int rp = carry + excl;
            row_ptr[idx] = rp;
            cursor[idx]  = rp;
        }
        carry += __shfl(incl, 63, 64);
    }
    if (lane == 0) row_ptr[N_NODES] = carry;
}

// Reorder edges by src: pairs[pos] = (dst, val).
__global__ __launch_bounds__(256) void fill_kernel(
    const int* __restrict__ src, const int* __restrict__ dst,
    const float* __restrict__ vals, int* __restrict__ cursor,
    int2* __restrict__ pairs)
{
    int e = blockIdx.x * 256 + threadIdx.x;
    if (e >= N_EDGES) return;
    int pos = atomicAdd(&cursor[src[e]], 1);
    pairs[pos] = make_int2(dst[e], __float_as_int(vals[e]));
}

// ---------------------------------------------------------------------------
// CSR gather aggregation: agg[n,:] = sum_{edges e with src==n} support[dst_e,:]*val_e
// F/4 threads per node, float4 accumulation in registers, one write per elem.
// ---------------------------------------------------------------------------
template <int F>
__global__ __launch_bounds__(256) void gather_kernel(
    const float* __restrict__ support, const int2* __restrict__ pairs,
    const int* __restrict__ row_ptr, float* __restrict__ agg)
{
    constexpr int TPN = F / 4;        // threads per node
    constexpr int NPB = 256 / TPN;    // nodes per block
    const int node = blockIdx.x * NPB + threadIdx.x / TPN;
    if (node >= N_NODES) return;
    const int lane = threadIdx.x % TPN;
    int i   = row_ptr[node];
    const int end = row_ptr[node + 1];

    float4 acc0 = {0, 0, 0, 0};
    float4 acc1 = {0, 0, 0, 0};

    // 2-way unroll for memory ILP (two independent gather chains)
    for (; i + 2 <= end; i += 2) {
        int2 p0 = pairs[i];
        int2 p1 = pairs[i + 1];
        float v0 = __int_as_float(p0.y);
        float v1 = __int_as_float(p1.y);
        const float4 m0 = *reinterpret_cast<const float4*>(
            support + (size_t)p0.x * F + lane * 4);
        const float4 m1 = *reinterpret_cast<const float4*>(
            support + (size_t)p1.x * F + lane * 4);
        acc0.x += m0.x * v0; acc0.y += m0.y * v0;
        acc0.z += m0.z * v0; acc0.w += m0.w * v0;
        acc1.x += m1.x * v1; acc1.y += m1.y * v1;
        acc1.z += m1.z * v1; acc1.w += m1.w * v1;
    }
    if (i < end) {
        int2 p = pairs[i];
        float v = __int_as_float(p.y);
        const float4 m = *reinterpret_cast<const float4*>(
            support + (size_t)p.x * F + lane * 4);
        acc0.x += m.x * v; acc0.y += m.y * v;
        acc0.z += m.z * v; acc0.w += m.w * v;
    }
    acc0.x += acc1.x; acc0.y += acc1.y; acc0.z += acc1.z; acc0.w += acc1.w;
    *reinterpret_cast<float4*>(agg + (size_t)node * F + lane * 4) = acc0;
}

// ---------------------------------------------------------------------------
// Row-wise log_softmax over 16 columns (with bias b3).
// ---------------------------------------------------------------------------
__global__ __launch_bounds__(256) void logsoftmax_kernel(
    const float* __restrict__ agg, const float* __restrict__ b3,
    float* __restrict__ out)
{
    int row = blockIdx.x * 256 + threadIdx.x;
    if (row >= N_NODES) return;
    float v[16];
    const float4* p = reinterpret_cast<const float4*>(agg + (size_t)row * 16);
#pragma unroll
    for (int i = 0; i < 4; ++i) {
        float4 q = p[i];
        v[i * 4 + 0] = q.x + b3[i * 4 + 0];
        v[i * 4 + 1] = q.y + b3[i * 4 + 1];
        v[i * 4 + 2] = q.z + b3[i * 4 + 2];
        v[i * 4 + 3] = q.w + b3[i * 4 + 3];
    }
    float mx = v[0];
#pragma unroll
    for (int i = 1; i < 16; ++i) mx = fmaxf(mx, v[i]);
    float s = 0.0f;
#pragma unroll
    for (int i = 0; i < 16; ++i) s += expf(v[i] - mx);
    float lse = mx + logf(s);
    float4* o = reinterpret_cast<float4*>(out + (size_t)row * 16);
#pragma unroll
    for (int i = 0; i < 4; ++i)
        o[i] = make_float4(v[i * 4 + 0] - lse, v[i * 4 + 1] - lse,
                           v[i * 4 + 2] - lse, v[i * 4 + 3] - lse);
}

// ---------------------------------------------------------------------------
extern "C" void kernel_launch(void* const* d_in, const int* in_sizes, int n_in,
                              void* d_out, int out_size, void* d_ws, size_t ws_size,
                              hipStream_t stream)
{
    const float* x         = (const float*)d_in[0];
    const float* edge_vals = (const float*)d_in[1];
    const float* W1 = (const float*)d_in[2];
    const float* b1 = (const float*)d_in[3];
    const float* W2 = (const float*)d_in[4];
    const float* b2 = (const float*)d_in[5];
    const float* W3 = (const float*)d_in[6];
    const float* b3 = (const float*)d_in[7];
    const float* We = (const float*)d_in[8];
    const float* be = (const float*)d_in[9];
    const int* esrc = (const int*)d_in[10];
    const int* edst = (const int*)d_in[11];

    float* out1 = (float*)d_out;                        // [50000,16]
    float* out2 = (float*)d_out + (size_t)N_NODES * 16; // [50000,64]

    // Workspace layout (bytes, 256-aligned):
    char* ws = (char*)d_ws;
    float* bufA    = (float*)(ws);                    // 25,600,000  [N,128] max
    float* bufB    = (float*)(ws + 25600000);         // 25,600,000  [N,128] max
    float* bufC    = (float*)(ws + 51200000);         //  3,200,000  [N,16]
    int*   counts  = (int*)  (ws + 54400000);         //    200,064
    int*   row_ptr = (int*)  (ws + 54600064);         //    200,064 (N+1 ints)
    int*   cursor  = (int*)  (ws + 54800128);         //    200,064
    int2*  pairs   = (int2*) (ws + 55000192);         //  6,400,000
    // total: 61,400,192 B

    const int MB = (N_NODES + 63) / 64;   // 782
    const int EB = (N_EDGES + 255) / 256; // 3125

    // --- CSR build (src-indexed), reused by all three layers ---
    hipMemsetAsync(counts, 0, (size_t)N_NODES * 4, stream);
    hist_kernel<<<EB, 256, 0, stream>>>(esrc, counts);
    scan_kernel<<<1, 64, 0, stream>>>(counts, row_ptr, cursor);
    fill_kernel<<<EB, 256, 0, stream>>>(esrc, edst, edge_vals, cursor, pairs);

    // 1. support1 = x @ W1                          -> bufA [N,128]
    gemm1_kernel<<<MB, 256, 0, stream>>>(x, W1, bufA);

    // 2. agg1 = CSR-gather(support1)                -> bufB [N,128]
    gather_kernel<128><<<(N_NODES * 32 + 255) / 256, 256, 0, stream>>>(
        bufA, pairs, row_ptr, bufB);

    // 3. support2 = relu(agg1 + b1) @ W2            -> bufA [N,64]
    gemm_small_kernel<128, 64, 4, 4, true, false><<<MB, 256, 0, stream>>>(
        bufB, W2, b1, nullptr, bufA, N_NODES);

    // 4. agg2 = CSR-gather(support2)                -> bufB [N,64]
    gather_kernel<64><<<(N_NODES * 16 + 255) / 256, 256, 0, stream>>>(
        bufA, pairs, row_ptr, bufB);

    // 5. out2 = relu(agg2 + b2) @ We + be           -> d_out tail
    gemm_small_kernel<64, 64, 4, 4, true, true><<<MB, 256, 0, stream>>>(
        bufB, We, b2, be, out2, N_NODES);

    // 6. support3 = relu(agg2 + b2) @ W3            -> bufA [N,16]
    gemm_small_kernel<64, 16, 4, 1, true, false><<<MB, 256, 0, stream>>>(
        bufB, W3, b2, nullptr, bufA, N_NODES);

    // 7. agg3 = CSR-gather(support3)                -> bufC [N,16]
    gather_kernel<16><<<(N_NODES * 4 + 255) / 256, 256, 0, stream>>>(
        bufA, pairs, row_ptr, bufC);

    // 8. out1 = log_softmax(agg3 + b3)              -> d_out head
    logsoftmax_kernel<<<(N_NODES + 255) / 256, 256, 0, stream>>>(bufC, b3, out1);
}

// Round 3
// 610.770 us; speedup vs baseline: 4.0894x; 1.4010x over previous
//
#include <hip/hip_runtime.h>
#include <math.h>

#define N_NODES 50000
#define N_EDGES 800000

// ---------------------------------------------------------------------------
// GEMM1: C[M,128] = A[M,500] @ B[500,128], fp32.
// ---------------------------------------------------------------------------
__global__ __launch_bounds__(256) void gemm1_kernel(
    const float* __restrict__ A, const float* __restrict__ B,
    float* __restrict__ C)
{
    constexpr int K = 500, N = 128, BM = 64, BK = 20;
    constexpr int PAD = BM + 4;
    __shared__ float As[BK * PAD];
    __shared__ float Bs[BK * N];

    const int t = threadIdx.x;
    const int row0 = blockIdx.x * BM;
    const int tx = t & 31;
    const int ty = t >> 5;

    float acc[8][4] = {};

    for (int k0 = 0; k0 < K; k0 += BK) {
#pragma unroll
        for (int i = 0; i < 5; ++i) {
            int idx = t + i * 256;
            int kk = idx % BK, m = idx / BK;
            int gr = row0 + m;
            float v = (gr < N_NODES) ? A[(size_t)gr * K + k0 + kk] : 0.0f;
            As[kk * PAD + m] = v;
        }
#pragma unroll
        for (int i = 0; i < 10; ++i) {
            int idx = t + i * 256;
            int kr = idx >> 7, n = idx & 127;
            Bs[kr * N + n] = B[(size_t)(k0 + kr) * N + n];
        }
        __syncthreads();
#pragma unroll
        for (int kk = 0; kk < BK; ++kk) {
            float a[8], b[4];
#pragma unroll
            for (int i = 0; i < 8; ++i) a[i] = As[kk * PAD + ty * 8 + i];
#pragma unroll
            for (int j = 0; j < 4; ++j) b[j] = Bs[kk * N + tx * 4 + j];
#pragma unroll
            for (int i = 0; i < 8; ++i)
#pragma unroll
                for (int j = 0; j < 4; ++j) acc[i][j] += a[i] * b[j];
        }
        __syncthreads();
    }

#pragma unroll
    for (int i = 0; i < 8; ++i) {
        int gr = row0 + ty * 8 + i;
        if (gr < N_NODES) {
            float4 v = make_float4(acc[i][0], acc[i][1], acc[i][2], acc[i][3]);
            *reinterpret_cast<float4*>(C + (size_t)gr * N + tx * 4) = v;
        }
    }
}

// ---------------------------------------------------------------------------
// Small-K GEMM: C[M,N] = f(A[M,K]) @ B[K,N] (+ bC), f = relu(a + bA[k]).
// ---------------------------------------------------------------------------
template <int K, int N, int TM, int TN, bool RELU_A, bool BIAS_C>
__global__ __launch_bounds__(256) void gemm_small_kernel(
    const float* __restrict__ A, const float* __restrict__ B,
    const float* __restrict__ bA, const float* __restrict__ bC,
    float* __restrict__ C, int M)
{
    constexpr int BM = 64;
    constexpr int BK = 32;
    constexpr int PAD = BM + 4;
    constexpr int RG = BM / TM;
    constexpr int CG = N / TN;
    static_assert(RG * CG == 256, "thread layout");
    static_assert(K % BK == 0, "K chunking");

    __shared__ float Bs[K * N];
    __shared__ float As[BK * PAD];

    const int t = threadIdx.x;
    const int row0 = blockIdx.x * BM;
    const int tx = t % CG;
    const int ty = t / CG;

    constexpr int BLOADS = (K * N) / 256;
#pragma unroll
    for (int i = 0; i < BLOADS; ++i) {
        int idx = t + i * 256;
        Bs[idx] = B[idx];
    }

    float acc[TM][TN] = {};

    for (int k0 = 0; k0 < K; k0 += BK) {
        float av[(BK * BM) / 256];
#pragma unroll
        for (int i = 0; i < (BK * BM) / 256; ++i) {
            int idx = t + i * 256;
            int kk = idx % BK, m = idx / BK;
            int gr = row0 + m;
            float v = (gr < M) ? A[(size_t)gr * K + k0 + kk] : 0.0f;
            if constexpr (RELU_A) {
                v += bA[k0 + kk];
                v = v > 0.0f ? v : 0.0f;
            }
            av[i] = v;
        }
        __syncthreads();
#pragma unroll
        for (int i = 0; i < (BK * BM) / 256; ++i) {
            int idx = t + i * 256;
            As[(idx % BK) * PAD + idx / BK] = av[i];
        }
        __syncthreads();
#pragma unroll
        for (int kk = 0; kk < BK; ++kk) {
            float a[TM], b[TN];
#pragma unroll
            for (int i = 0; i < TM; ++i) a[i] = As[kk * PAD + ty * TM + i];
#pragma unroll
            for (int j = 0; j < TN; ++j) b[j] = Bs[(k0 + kk) * N + tx * TN + j];
#pragma unroll
            for (int i = 0; i < TM; ++i)
#pragma unroll
                for (int j = 0; j < TN; ++j) acc[i][j] += a[i] * b[j];
        }
    }

#pragma unroll
    for (int i = 0; i < TM; ++i) {
        int gr = row0 + ty * TM + i;
        if (gr < M) {
            if constexpr (TN == 4) {
                float4 v;
                v.x = acc[i][0]; v.y = acc[i][1]; v.z = acc[i][2]; v.w = acc[i][3];
                if constexpr (BIAS_C) {
                    v.x += bC[tx * 4 + 0]; v.y += bC[tx * 4 + 1];
                    v.z += bC[tx * 4 + 2]; v.w += bC[tx * 4 + 3];
                }
                *reinterpret_cast<float4*>(C + (size_t)gr * N + tx * 4) = v;
            } else {
#pragma unroll
                for (int j = 0; j < TN; ++j) {
                    float v = acc[i][j];
                    if constexpr (BIAS_C) v += bC[tx * TN + j];
                    C[(size_t)gr * N + tx * TN + j] = v;
                }
            }
        }
    }
}

// ---------------------------------------------------------------------------
// CSR build (per launch; reused by all 3 aggregation layers).
// ---------------------------------------------------------------------------
__global__ __launch_bounds__(256) void hist_kernel(
    const int* __restrict__ src, int* __restrict__ counts)
{
    int e = blockIdx.x * 256 + threadIdx.x;
    if (e < N_EDGES) atomicAdd(&counts[src[e]], 1);
}

// Single-block 1024-thread exclusive scan: counts[0..N) -> row_ptr/cursor.
// Pass 1: per-thread chunk sum; block scan (wave shuffle + LDS); pass 2:
// re-read counts (L2-hot) and emit running prefix. Chain = 2 load latencies.
__global__ __launch_bounds__(1024) void scan_kernel(
    const int* __restrict__ counts, int* __restrict__ row_ptr,
    int* __restrict__ cursor)
{
    constexpr int T = 1024;
    constexpr int C = (N_NODES + T - 1) / T;   // 49 elems per thread
    const int t = threadIdx.x;
    const int lane = t & 63, wave = t >> 6;
    const int base = t * C;

    // pass 1: local chunk sum
    int s = 0;
#pragma unroll 4
    for (int i = 0; i < C; ++i) {
        int idx = base + i;
        if (idx < N_NODES) s += counts[idx];
    }

    // wave-level inclusive scan of thread sums
    int incl = s;
#pragma unroll
    for (int off = 1; off < 64; off <<= 1) {
        int n = __shfl_up(incl, off, 64);
        if (lane >= off) incl += n;
    }

    __shared__ int wsum[16];
    if (lane == 63) wsum[wave] = incl;
    __syncthreads();

    // scan the 16 wave sums (first wave, lanes 0..15, lockstep-safe)
    if (t < 16) {
        int v = wsum[t];
        int inc = v;
#pragma unroll
        for (int off = 1; off < 16; off <<= 1) {
            int n = __shfl_up(inc, off, 64);
            if (t >= off) inc += n;
        }
        wsum[t] = inc - v;   // exclusive wave offset
    }
    __syncthreads();

    // pass 2: emit running exclusive prefix for this thread's chunk
    int run = wsum[wave] + (incl - s);
#pragma unroll 4
    for (int i = 0; i < C; ++i) {
        int idx = base + i;
        if (idx < N_NODES) {
            row_ptr[idx] = run;
            cursor[idx]  = run;
            run += counts[idx];
        }
    }
    if (t == T - 1) row_ptr[N_NODES] = run;   // == total (last chunk is past N)
}

// Reorder edges by src: pairs[pos] = (dst, val).
__global__ __launch_bounds__(256) void fill_kernel(
    const int* __restrict__ src, const int* __restrict__ dst,
    const float* __restrict__ vals, int* __restrict__ cursor,
    int2* __restrict__ pairs)
{
    int e = blockIdx.x * 256 + threadIdx.x;
    if (e >= N_EDGES) return;
    int pos = atomicAdd(&cursor[src[e]], 1);
    pairs[pos] = make_int2(dst[e], __float_as_int(vals[e]));
}

// ---------------------------------------------------------------------------
// CSR gather aggregation: agg[n,:] = sum_{edges e with src==n} support[dst_e,:]*val_e
// ---------------------------------------------------------------------------
template <int F>
__global__ __launch_bounds__(256) void gather_kernel(
    const float* __restrict__ support, const int2* __restrict__ pairs,
    const int* __restrict__ row_ptr, float* __restrict__ agg)
{
    constexpr int TPN = F / 4;        // threads per node
    constexpr int NPB = 256 / TPN;    // nodes per block
    const int node = blockIdx.x * NPB + threadIdx.x / TPN;
    if (node >= N_NODES) return;
    const int lane = threadIdx.x % TPN;
    int i   = row_ptr[node];
    const int end = row_ptr[node + 1];

    float4 acc0 = {0, 0, 0, 0};
    float4 acc1 = {0, 0, 0, 0};

    for (; i + 2 <= end; i += 2) {
        int2 p0 = pairs[i];
        int2 p1 = pairs[i + 1];
        float v0 = __int_as_float(p0.y);
        float v1 = __int_as_float(p1.y);
        const float4 m0 = *reinterpret_cast<const float4*>(
            support + (size_t)p0.x * F + lane * 4);
        const float4 m1 = *reinterpret_cast<const float4*>(
            support + (size_t)p1.x * F + lane * 4);
        acc0.x += m0.x * v0; acc0.y += m0.y * v0;
        acc0.z += m0.z * v0; acc0.w += m0.w * v0;
        acc1.x += m1.x * v1; acc1.y += m1.y * v1;
        acc1.z += m1.z * v1; acc1.w += m1.w * v1;
    }
    if (i < end) {
        int2 p = pairs[i];
        float v = __int_as_float(p.y);
        const float4 m = *reinterpret_cast<const float4*>(
            support + (size_t)p.x * F + lane * 4);
        acc0.x += m.x * v; acc0.y += m.y * v;
        acc0.z += m.z * v; acc0.w += m.w * v;
    }
    acc0.x += acc1.x; acc0.y += acc1.y; acc0.z += acc1.z; acc0.w += acc1.w;
    *reinterpret_cast<float4*>(agg + (size_t)node * F + lane * 4) = acc0;
}

// ---------------------------------------------------------------------------
// Row-wise log_softmax over 16 columns (with bias b3).
// ---------------------------------------------------------------------------
__global__ __launch_bounds__(256) void logsoftmax_kernel(
    const float* __restrict__ agg, const float* __restrict__ b3,
    float* __restrict__ out)
{
    int row = blockIdx.x * 256 + threadIdx.x;
    if (row >= N_NODES) return;
    float v[16];
    const float4* p = reinterpret_cast<const float4*>(agg + (size_t)row * 16);
#pragma unroll
    for (int i = 0; i < 4; ++i) {
        float4 q = p[i];
        v[i * 4 + 0] = q.x + b3[i * 4 + 0];
        v[i * 4 + 1] = q.y + b3[i * 4 + 1];
        v[i * 4 + 2] = q.z + b3[i * 4 + 2];
        v[i * 4 + 3] = q.w + b3[i * 4 + 3];
    }
    float mx = v[0];
#pragma unroll
    for (int i = 1; i < 16; ++i) mx = fmaxf(mx, v[i]);
    float s = 0.0f;
#pragma unroll
    for (int i = 0; i < 16; ++i) s += expf(v[i] - mx);
    float lse = mx + logf(s);
    float4* o = reinterpret_cast<float4*>(out + (size_t)row * 16);
#pragma unroll
    for (int i = 0; i < 4; ++i)
        o[i] = make_float4(v[i * 4 + 0] - lse, v[i * 4 + 1] - lse,
                           v[i * 4 + 2] - lse, v[i * 4 + 3] - lse);
}

// ---------------------------------------------------------------------------
extern "C" void kernel_launch(void* const* d_in, const int* in_sizes, int n_in,
                              void* d_out, int out_size, void* d_ws, size_t ws_size,
                              hipStream_t stream)
{
    const float* x         = (const float*)d_in[0];
    const float* edge_vals = (const float*)d_in[1];
    const float* W1 = (const float*)d_in[2];
    const float* b1 = (const float*)d_in[3];
    const float* W2 = (const float*)d_in[4];
    const float* b2 = (const float*)d_in[5];
    const float* W3 = (const float*)d_in[6];
    const float* b3 = (const float*)d_in[7];
    const float* We = (const float*)d_in[8];
    const float* be = (const float*)d_in[9];
    const int* esrc = (const int*)d_in[10];
    const int* edst = (const int*)d_in[11];

    float* out1 = (float*)d_out;                        // [50000,16]
    float* out2 = (float*)d_out + (size_t)N_NODES * 16; // [50000,64]

    char* ws = (char*)d_ws;
    float* bufA    = (float*)(ws);                    // 25,600,000  [N,128] max
    float* bufB    = (float*)(ws + 25600000);         // 25,600,000  [N,128] max
    float* bufC    = (float*)(ws + 51200000);         //  3,200,000  [N,16]
    int*   counts  = (int*)  (ws + 54400000);         //    200,064
    int*   row_ptr = (int*)  (ws + 54600064);         //    200,064 (N+1 ints)
    int*   cursor  = (int*)  (ws + 54800128);         //    200,064
    int2*  pairs   = (int2*) (ws + 55000192);         //  6,400,000
    // total: 61,400,192 B

    const int MB = (N_NODES + 63) / 64;   // 782
    const int EB = (N_EDGES + 255) / 256; // 3125

    // --- CSR build (src-indexed), reused by all three layers ---
    hipMemsetAsync(counts, 0, (size_t)N_NODES * 4, stream);
    hist_kernel<<<EB, 256, 0, stream>>>(esrc, counts);
    scan_kernel<<<1, 1024, 0, stream>>>(counts, row_ptr, cursor);
    fill_kernel<<<EB, 256, 0, stream>>>(esrc, edst, edge_vals, cursor, pairs);

    // 1. support1 = x @ W1                          -> bufA [N,128]
    gemm1_kernel<<<MB, 256, 0, stream>>>(x, W1, bufA);

    // 2. agg1 = CSR-gather(support1)                -> bufB [N,128]
    gather_kernel<128><<<(N_NODES * 32 + 255) / 256, 256, 0, stream>>>(
        bufA, pairs, row_ptr, bufB);

    // 3. support2 = relu(agg1 + b1) @ W2            -> bufA [N,64]
    gemm_small_kernel<128, 64, 4, 4, true, false><<<MB, 256, 0, stream>>>(
        bufB, W2, b1, nullptr, bufA, N_NODES);

    // 4. agg2 = CSR-gather(support2)                -> bufB [N,64]
    gather_kernel<64><<<(N_NODES * 16 + 255) / 256, 256, 0, stream>>>(
        bufA, pairs, row_ptr, bufB);

    // 5. out2 = relu(agg2 + b2) @ We + be           -> d_out tail
    gemm_small_kernel<64, 64, 4, 4, true, true><<<MB, 256, 0, stream>>>(
        bufB, We, b2, be, out2, N_NODES);

    // 6. support3 = relu(agg2 + b2) @ W3            -> bufA [N,16]
    gemm_small_kernel<64, 16, 4, 1, true, false><<<MB, 256, 0, stream>>>(
        bufB, W3, b2, nullptr, bufA, N_NODES);

    // 7. agg3 = CSR-gather(support3)                -> bufC [N,16]
    gather_kernel<16><<<(N_NODES * 4 + 255) / 256, 256, 0, stream>>>(
        bufA, pairs, row_ptr, bufC);

    // 8. out1 = log_softmax(agg3 + b3)              -> d_out head
    logsoftmax_kernel<<<(N_NODES + 255) / 256, 256, 0, stream>>>(bufC, b3, out1);
}

// Round 4
// 530.480 us; speedup vs baseline: 4.7084x; 1.1514x over previous
//
#include <hip/hip_runtime.h>
#include <math.h>

#define N_NODES 50000
#define N_EDGES 800000

typedef __attribute__((ext_vector_type(8))) short bf16x8;   // 4 VGPRs, MFMA A/B frag
typedef __attribute__((ext_vector_type(4))) float f32x4;    // MFMA C/D frag

__device__ inline unsigned short f2bf(float f) {   // RNE float->bf16
    unsigned u = __float_as_uint(f);
    unsigned r = (u + 0x7fffu + ((u >> 16) & 1u)) >> 16;
    return (unsigned short)r;
}

// ---------------------------------------------------------------------------
// One-time: W1 [500,128] fp32 -> W1bf [128,512] bf16 (transposed, zero-padded)
// ---------------------------------------------------------------------------
__global__ __launch_bounds__(256) void convert_w1_kernel(
    const float* __restrict__ W1, unsigned short* __restrict__ W1bf)
{
    int t = blockIdx.x * 256 + threadIdx.x;   // 128*512 = 65536 threads
    int n = t >> 9, k = t & 511;
    float v = (k < 500) ? W1[k * 128 + n] : 0.0f;
    W1bf[t] = f2bf(v);
}

// ---------------------------------------------------------------------------
// GEMM1 via bf16 MFMA: C[M,128] = A[M,500] @ W1, output bf16.
// Block tile 64x128, 4 waves (2x2), each wave 32x64 = 2x4 MFMA tiles of 16x16.
// A staged fp32->bf16 into LDS (register-prefetched); B frags from global
// (W1bf is 128 KB, L2-resident). K padded 500->512, 16 steps of BK=32.
// Frag layouts (learn_hip m89-verified):
//   A[m=lane&15][k=(lane>>4)*8+j], B[k=(lane>>4)*8+j][n=lane&15],
//   D: row=(lane>>4)*4+reg, col=lane&15.
// ---------------------------------------------------------------------------
__global__ __launch_bounds__(256) void gemm1_mfma_kernel(
    const float* __restrict__ A,            // [M,500] fp32
    const unsigned short* __restrict__ Bt,  // [128,512] bf16 (B^T, padded)
    unsigned short* __restrict__ C)         // [M,128] bf16
{
    constexpr int K = 500, N = 128, BM = 64;
    constexpr int LDA = 56;  // bf16/row: 112 B rows -> 28-bank stride, 16B-aligned,
                             // conflict-free b128 frag reads (2-way max)
    __shared__ __align__(16) unsigned short As[BM * LDA];

    const int t = threadIdx.x;
    const int row0 = blockIdx.x * BM;
    const int lane = t & 63;
    const int wave = t >> 6;
    const int wm = (wave & 1) * 32;
    const int wn = (wave >> 1) * 64;
    const int l15 = lane & 15;
    const int l4  = lane >> 4;

    // staging: thread handles rows m0=t>>3 and m0+32, k-chunk kq (float4)
    const int m0 = t >> 3, kq = t & 7;
    const int m1 = m0 + 32;
    const float* arow0 = A + (size_t)(row0 + m0) * K;
    const float* arow1 = A + (size_t)(row0 + m1) * K;
    const bool rv0 = (row0 + m0) < N_NODES;
    const bool rv1 = (row0 + m1) < N_NODES;

    const f32x4 zero = {0.0f, 0.0f, 0.0f, 0.0f};
    f32x4 acc[2][4];
#pragma unroll
    for (int i = 0; i < 2; ++i)
#pragma unroll
        for (int j = 0; j < 4; ++j) acc[i][j] = zero;

    float4 pf0, pf1;
    auto ldA = [&](int k0, float4& d, const float* row, bool rowok) {
        int k = k0 + kq * 4;
        if (rowok && k < K) d = *reinterpret_cast<const float4*>(row + k);
        else d = make_float4(0.0f, 0.0f, 0.0f, 0.0f);
    };
    ldA(0, pf0, arow0, rv0);
    ldA(0, pf1, arow1, rv1);

    for (int s = 0; s < 16; ++s) {
        const int k0 = s * 32;
        __syncthreads();   // prior step's frag reads done
        {
            unsigned short h[4];
            h[0] = f2bf(pf0.x); h[1] = f2bf(pf0.y);
            h[2] = f2bf(pf0.z); h[3] = f2bf(pf0.w);
            *reinterpret_cast<uint2*>(&As[m0 * LDA + kq * 4]) =
                *reinterpret_cast<uint2*>(h);
            h[0] = f2bf(pf1.x); h[1] = f2bf(pf1.y);
            h[2] = f2bf(pf1.z); h[3] = f2bf(pf1.w);
            *reinterpret_cast<uint2*>(&As[m1 * LDA + kq * 4]) =
                *reinterpret_cast<uint2*>(h);
        }
        __syncthreads();   // As visible
        if (s < 15) {      // prefetch next A chunk (overlaps MFMAs below)
            ldA(k0 + 32, pf0, arow0, rv0);
            ldA(k0 + 32, pf1, arow1, rv1);
        }

        bf16x8 af[2];
#pragma unroll
        for (int i = 0; i < 2; ++i) {
            int m = wm + i * 16 + l15;
            af[i] = *reinterpret_cast<const bf16x8*>(&As[m * LDA + l4 * 8]);
        }
        bf16x8 bfr[4];
#pragma unroll
        for (int j = 0; j < 4; ++j) {
            int n = wn + j * 16 + l15;
            bfr[j] = *reinterpret_cast<const bf16x8*>(
                Bt + (size_t)n * 512 + k0 + l4 * 8);
        }
#pragma unroll
        for (int i = 0; i < 2; ++i)
#pragma unroll
            for (int j = 0; j < 4; ++j)
                acc[i][j] = __builtin_amdgcn_mfma_f32_16x16x32_bf16(
                    af[i], bfr[j], acc[i][j], 0, 0, 0);
    }

#pragma unroll
    for (int i = 0; i < 2; ++i) {
#pragma unroll
        for (int r = 0; r < 4; ++r) {
            int row = row0 + wm + i * 16 + l4 * 4 + r;
            if (row < N_NODES) {
#pragma unroll
                for (int j = 0; j < 4; ++j) {
                    int col = wn + j * 16 + l15;
                    C[(size_t)row * N + col] = f2bf(acc[i][j][r]);
                }
            }
        }
    }
}

// ---------------------------------------------------------------------------
// Small-K GEMM: C[M,N] = f(A[M,K]) @ B[K,N] (+ bC), f = relu(a + bA[k]).
// ---------------------------------------------------------------------------
template <int K, int N, int TM, int TN, bool RELU_A, bool BIAS_C>
__global__ __launch_bounds__(256) void gemm_small_kernel(
    const float* __restrict__ A, const float* __restrict__ B,
    const float* __restrict__ bA, const float* __restrict__ bC,
    float* __restrict__ C, int M)
{
    constexpr int BM = 64;
    constexpr int BK = 32;
    constexpr int PAD = BM + 4;
    constexpr int RG = BM / TM;
    constexpr int CG = N / TN;
    static_assert(RG * CG == 256, "thread layout");
    static_assert(K % BK == 0, "K chunking");

    __shared__ float Bs[K * N];
    __shared__ float As[BK * PAD];

    const int t = threadIdx.x;
    const int row0 = blockIdx.x * BM;
    const int tx = t % CG;
    const int ty = t / CG;

    constexpr int BLOADS = (K * N) / 256;
#pragma unroll
    for (int i = 0; i < BLOADS; ++i) {
        int idx = t + i * 256;
        Bs[idx] = B[idx];
    }

    float acc[TM][TN] = {};

    for (int k0 = 0; k0 < K; k0 += BK) {
        float av[(BK * BM) / 256];
#pragma unroll
        for (int i = 0; i < (BK * BM) / 256; ++i) {
            int idx = t + i * 256;
            int kk = idx % BK, m = idx / BK;
            int gr = row0 + m;
            float v = (gr < M) ? A[(size_t)gr * K + k0 + kk] : 0.0f;
            if constexpr (RELU_A) {
                v += bA[k0 + kk];
                v = v > 0.0f ? v : 0.0f;
            }
            av[i] = v;
        }
        __syncthreads();
#pragma unroll
        for (int i = 0; i < (BK * BM) / 256; ++i) {
            int idx = t + i * 256;
            As[(idx % BK) * PAD + idx / BK] = av[i];
        }
        __syncthreads();
#pragma unroll
        for (int kk = 0; kk < BK; ++kk) {
            float a[TM], b[TN];
#pragma unroll
            for (int i = 0; i < TM; ++i) a[i] = As[kk * PAD + ty * TM + i];
#pragma unroll
            for (int j = 0; j < TN; ++j) b[j] = Bs[(k0 + kk) * N + tx * TN + j];
#pragma unroll
            for (int i = 0; i < TM; ++i)
#pragma unroll
                for (int j = 0; j < TN; ++j) acc[i][j] += a[i] * b[j];
        }
    }

#pragma unroll
    for (int i = 0; i < TM; ++i) {
        int gr = row0 + ty * TM + i;
        if (gr < M) {
            if constexpr (TN == 4) {
                float4 v;
                v.x = acc[i][0]; v.y = acc[i][1]; v.z = acc[i][2]; v.w = acc[i][3];
                if constexpr (BIAS_C) {
                    v.x += bC[tx * 4 + 0]; v.y += bC[tx * 4 + 1];
                    v.z += bC[tx * 4 + 2]; v.w += bC[tx * 4 + 3];
                }
                *reinterpret_cast<float4*>(C + (size_t)gr * N + tx * 4) = v;
            } else {
#pragma unroll
                for (int j = 0; j < TN; ++j) {
                    float v = acc[i][j];
                    if constexpr (BIAS_C) v += bC[tx * TN + j];
                    C[(size_t)gr * N + tx * TN + j] = v;
                }
            }
        }
    }
}

// ---------------------------------------------------------------------------
// CSR build (per launch; reused by all 3 aggregation layers).
// ---------------------------------------------------------------------------
__global__ __launch_bounds__(256) void hist_kernel(
    const int* __restrict__ src, int* __restrict__ counts)
{
    int e = blockIdx.x * 256 + threadIdx.x;
    if (e < N_EDGES) atomicAdd(&counts[src[e]], 1);
}

// Single-block 1024-thread exclusive scan: counts[0..N) -> row_ptr/cursor.
__global__ __launch_bounds__(1024) void scan_kernel(
    const int* __restrict__ counts, int* __restrict__ row_ptr,
    int* __restrict__ cursor)
{
    constexpr int T = 1024;
    constexpr int C = (N_NODES + T - 1) / T;   // 49
    const int t = threadIdx.x;
    const int lane = t & 63, wave = t >> 6;
    const int base = t * C;

    int s = 0;
#pragma unroll 4
    for (int i = 0; i < C; ++i) {
        int idx = base + i;
        if (idx < N_NODES) s += counts[idx];
    }

    int incl = s;
#pragma unroll
    for (int off = 1; off < 64; off <<= 1) {
        int n = __shfl_up(incl, off, 64);
        if (lane >= off) incl += n;
    }

    __shared__ int wsum[16];
    if (lane == 63) wsum[wave] = incl;
    __syncthreads();

    if (t < 16) {
        int v = wsum[t];
        int inc = v;
#pragma unroll
        for (int off = 1; off < 16; off <<= 1) {
            int n = __shfl_up(inc, off, 64);
            if (t >= off) inc += n;
        }
        wsum[t] = inc - v;
    }
    __syncthreads();

    int run = wsum[wave] + (incl - s);
#pragma unroll 4
    for (int i = 0; i < C; ++i) {
        int idx = base + i;
        if (idx < N_NODES) {
            row_ptr[idx] = run;
            cursor[idx]  = run;
            run += counts[idx];
        }
    }
    if (t == T - 1) row_ptr[N_NODES] = run;
}

__global__ __launch_bounds__(256) void fill_kernel(
    const int* __restrict__ src, const int* __restrict__ dst,
    const float* __restrict__ vals, int* __restrict__ cursor,
    int2* __restrict__ pairs)
{
    int e = blockIdx.x * 256 + threadIdx.x;
    if (e >= N_EDGES) return;
    int pos = atomicAdd(&cursor[src[e]], 1);
    pairs[pos] = make_int2(dst[e], __float_as_int(vals[e]));
}

// ---------------------------------------------------------------------------
// CSR gather, bf16 support (F=128): 16 lanes/node, 16 B (8 feats) per lane.
// ---------------------------------------------------------------------------
__global__ __launch_bounds__(256) void gather128_bf16_kernel(
    const unsigned short* __restrict__ support, const int2* __restrict__ pairs,
    const int* __restrict__ row_ptr, float* __restrict__ agg)
{
    const int node = blockIdx.x * 16 + (threadIdx.x >> 4);
    if (node >= N_NODES) return;
    const int lane = threadIdx.x & 15;
    int i = row_ptr[node];
    const int end = row_ptr[node + 1];

    float acc[8] = {};
    for (; i + 2 <= end; i += 2) {
        int2 p0 = pairs[i], p1 = pairs[i + 1];
        float v0 = __int_as_float(p0.y), v1 = __int_as_float(p1.y);
        uint4 r0 = *reinterpret_cast<const uint4*>(
            support + (size_t)p0.x * 128 + lane * 8);
        uint4 r1 = *reinterpret_cast<const uint4*>(
            support + (size_t)p1.x * 128 + lane * 8);
        unsigned w0[4] = {r0.x, r0.y, r0.z, r0.w};
        unsigned w1[4] = {r1.x, r1.y, r1.z, r1.w};
#pragma unroll
        for (int j = 0; j < 4; ++j) {
            acc[2 * j]     += __uint_as_float(w0[j] << 16) * v0;
            acc[2 * j + 1] += __uint_as_float(w0[j] & 0xffff0000u) * v0;
            acc[2 * j]     += __uint_as_float(w1[j] << 16) * v1;
            acc[2 * j + 1] += __uint_as_float(w1[j] & 0xffff0000u) * v1;
        }
    }
    if (i < end) {
        int2 p = pairs[i];
        float v = __int_as_float(p.y);
        uint4 r = *reinterpret_cast<const uint4*>(
            support + (size_t)p.x * 128 + lane * 8);
        unsigned w[4] = {r.x, r.y, r.z, r.w};
#pragma unroll
        for (int j = 0; j < 4; ++j) {
            acc[2 * j]     += __uint_as_float(w[j] << 16) * v;
            acc[2 * j + 1] += __uint_as_float(w[j] & 0xffff0000u) * v;
        }
    }
    float4 o0 = {acc[0], acc[1], acc[2], acc[3]};
    float4 o1 = {acc[4], acc[5], acc[6], acc[7]};
    float4* op = reinterpret_cast<float4*>(agg + (size_t)node * 128 + lane * 8);
    op[0] = o0; op[1] = o1;
}

// fp32 gather for F = 64 / 16 (support2/3 remain fp32).
template <int F>
__global__ __launch_bounds__(256) void gather_kernel(
    const float* __restrict__ support, const int2* __restrict__ pairs,
    const int* __restrict__ row_ptr, float* __restrict__ agg)
{
    constexpr int TPN = F / 4;
    constexpr int NPB = 256 / TPN;
    const int node = blockIdx.x * NPB + threadIdx.x / TPN;
    if (node >= N_NODES) return;
    const int lane = threadIdx.x % TPN;
    int i = row_ptr[node];
    const int end = row_ptr[node + 1];

    float4 acc0 = {0, 0, 0, 0};
    float4 acc1 = {0, 0, 0, 0};

    for (; i + 2 <= end; i += 2) {
        int2 p0 = pairs[i];
        int2 p1 = pairs[i + 1];
        float v0 = __int_as_float(p0.y);
        float v1 = __int_as_float(p1.y);
        const float4 m0 = *reinterpret_cast<const float4*>(
            support + (size_t)p0.x * F + lane * 4);
        const float4 m1 = *reinterpret_cast<const float4*>(
            support + (size_t)p1.x * F + lane * 4);
        acc0.x += m0.x * v0; acc0.y += m0.y * v0;
        acc0.z += m0.z * v0; acc0.w += m0.w * v0;
        acc1.x += m1.x * v1; acc1.y += m1.y * v1;
        acc1.z += m1.z * v1; acc1.w += m1.w * v1;
    }
    if (i < end) {
        int2 p = pairs[i];
        float v = __int_as_float(p.y);
        const float4 m = *reinterpret_cast<const float4*>(
            support + (size_t)p.x * F + lane * 4);
        acc0.x += m.x * v; acc0.y += m.y * v;
        acc0.z += m.z * v; acc0.w += m.w * v;
    }
    acc0.x += acc1.x; acc0.y += acc1.y; acc0.z += acc1.z; acc0.w += acc1.w;
    *reinterpret_cast<float4*>(agg + (size_t)node * F + lane * 4) = acc0;
}

// ---------------------------------------------------------------------------
// Row-wise log_softmax over 16 columns (with bias b3).
// ---------------------------------------------------------------------------
__global__ __launch_bounds__(256) void logsoftmax_kernel(
    const float* __restrict__ agg, const float* __restrict__ b3,
    float* __restrict__ out)
{
    int row = blockIdx.x * 256 + threadIdx.x;
    if (row >= N_NODES) return;
    float v[16];
    const float4* p = reinterpret_cast<const float4*>(agg + (size_t)row * 16);
#pragma unroll
    for (int i = 0; i < 4; ++i) {
        float4 q = p[i];
        v[i * 4 + 0] = q.x + b3[i * 4 + 0];
        v[i * 4 + 1] = q.y + b3[i * 4 + 1];
        v[i * 4 + 2] = q.z + b3[i * 4 + 2];
        v[i * 4 + 3] = q.w + b3[i * 4 + 3];
    }
    float mx = v[0];
#pragma unroll
    for (int i = 1; i < 16; ++i) mx = fmaxf(mx, v[i]);
    float s = 0.0f;
#pragma unroll
    for (int i = 0; i < 16; ++i) s += expf(v[i] - mx);
    float lse = mx + logf(s);
    float4* o = reinterpret_cast<float4*>(out + (size_t)row * 16);
#pragma unroll
    for (int i = 0; i < 4; ++i)
        o[i] = make_float4(v[i * 4 + 0] - lse, v[i * 4 + 1] - lse,
                           v[i * 4 + 2] - lse, v[i * 4 + 3] - lse);
}

// ---------------------------------------------------------------------------
extern "C" void kernel_launch(void* const* d_in, const int* in_sizes, int n_in,
                              void* d_out, int out_size, void* d_ws, size_t ws_size,
                              hipStream_t stream)
{
    const float* x         = (const float*)d_in[0];
    const float* edge_vals = (const float*)d_in[1];
    const float* W1 = (const float*)d_in[2];
    const float* b1 = (const float*)d_in[3];
    const float* W2 = (const float*)d_in[4];
    const float* b2 = (const float*)d_in[5];
    const float* W3 = (const float*)d_in[6];
    const float* b3 = (const float*)d_in[7];
    const float* We = (const float*)d_in[8];
    const float* be = (const float*)d_in[9];
    const int* esrc = (const int*)d_in[10];
    const int* edst = (const int*)d_in[11];

    float* out1 = (float*)d_out;                        // [50000,16]
    float* out2 = (float*)d_out + (size_t)N_NODES * 16; // [50000,64]

    char* ws = (char*)d_ws;
    float* bufA    = (float*)(ws);                    // 25,600,000
    float* bufB    = (float*)(ws + 25600000);         // 25,600,000
    float* bufC    = (float*)(ws + 51200000);         //  3,200,000
    int*   counts  = (int*)  (ws + 54400000);         //    200,064
    int*   row_ptr = (int*)  (ws + 54600064);         //    200,064
    int*   cursor  = (int*)  (ws + 54800128);         //    200,064
    int2*  pairs   = (int2*) (ws + 55000192);         //  6,400,000
    // total: 61,400,192 B (unchanged from round 2/3)

    // W1bf [128,512] bf16 = 131,072 B lives in bufC (free until step 7);
    // support1 bf16 [N,128] = 12.8 MB lives in bufA.
    unsigned short* W1bf   = (unsigned short*)bufC;
    unsigned short* sup1bf = (unsigned short*)bufA;

    const int MB = (N_NODES + 63) / 64;   // 782
    const int EB = (N_EDGES + 255) / 256; // 3125

    // --- one-time weight prep + CSR build ---
    convert_w1_kernel<<<256, 256, 0, stream>>>(W1, W1bf);
    hipMemsetAsync(counts, 0, (size_t)N_NODES * 4, stream);
    hist_kernel<<<EB, 256, 0, stream>>>(esrc, counts);
    scan_kernel<<<1, 1024, 0, stream>>>(counts, row_ptr, cursor);
    fill_kernel<<<EB, 256, 0, stream>>>(esrc, edst, edge_vals, cursor, pairs);

    // 1. support1 = x @ W1 (bf16 MFMA)              -> bufA [N,128] bf16
    gemm1_mfma_kernel<<<MB, 256, 0, stream>>>(x, W1bf, sup1bf);

    // 2. agg1 = CSR-gather(support1 bf16)           -> bufB [N,128] fp32
    gather128_bf16_kernel<<<(N_NODES + 15) / 16, 256, 0, stream>>>(
        sup1bf, pairs, row_ptr, bufB);

    // 3. support2 = relu(agg1 + b1) @ W2            -> bufA [N,64] fp32
    gemm_small_kernel<128, 64, 4, 4, true, false><<<MB, 256, 0, stream>>>(
        bufB, W2, b1, nullptr, bufA, N_NODES);

    // 4. agg2 = CSR-gather(support2)                -> bufB [N,64]
    gather_kernel<64><<<(N_NODES * 16 + 255) / 256, 256, 0, stream>>>(
        bufA, pairs, row_ptr, bufB);

    // 5. out2 = relu(agg2 + b2) @ We + be           -> d_out tail
    gemm_small_kernel<64, 64, 4, 4, true, true><<<MB, 256, 0, stream>>>(
        bufB, We, b2, be, out2, N_NODES);

    // 6. support3 = relu(agg2 + b2) @ W3            -> bufA [N,16]
    gemm_small_kernel<64, 16, 4, 1, true, false><<<MB, 256, 0, stream>>>(
        bufB, W3, b2, nullptr, bufA, N_NODES);

    // 7. agg3 = CSR-gather(support3)                -> bufC [N,16] (over W1bf, done)
    gather_kernel<16><<<(N_NODES * 4 + 255) / 256, 256, 0, stream>>>(
        bufA, pairs, row_ptr, bufC);

    // 8. out1 = log_softmax(agg3 + b3)              -> d_out head
    logsoftmax_kernel<<<(N_NODES + 255) / 256, 256, 0, stream>>>(bufC, b3, out1);
}

// Round 5
// 412.239 us; speedup vs baseline: 6.0588x; 1.2868x over previous
//
#include <hip/hip_runtime.h>
#include <math.h>

#define N_NODES 50000
#define N_EDGES 800000

typedef __attribute__((ext_vector_type(8))) short bf16x8;   // 4 VGPRs, MFMA A/B frag
typedef __attribute__((ext_vector_type(4))) float f32x4;    // MFMA C/D frag

__device__ inline unsigned short f2bf(float f) {   // RNE float->bf16
    unsigned u = __float_as_uint(f);
    unsigned r = (u + 0x7fffu + ((u >> 16) & 1u)) >> 16;
    return (unsigned short)r;
}

// ---------------------------------------------------------------------------
// One-time: W1 [500,128] fp32 -> W1bf [128,512] bf16 (transposed, zero-padded)
// ---------------------------------------------------------------------------
__global__ __launch_bounds__(256) void convert_w1_kernel(
    const float* __restrict__ W1, unsigned short* __restrict__ W1bf)
{
    int t = blockIdx.x * 256 + threadIdx.x;   // 128*512 = 65536 threads
    int n = t >> 9, k = t & 511;
    float v = (k < 500) ? W1[k * 128 + n] : 0.0f;
    W1bf[t] = f2bf(v);
}

// ---------------------------------------------------------------------------
// GEMM1 via bf16 MFMA: C[M,128] = A[M,500] @ W1, output bf16.
// ---------------------------------------------------------------------------
__global__ __launch_bounds__(256) void gemm1_mfma_kernel(
    const float* __restrict__ A,            // [M,500] fp32
    const unsigned short* __restrict__ Bt,  // [128,512] bf16 (B^T, padded)
    unsigned short* __restrict__ C)         // [M,128] bf16
{
    constexpr int K = 500, N = 128, BM = 64;
    constexpr int LDA = 56;
    __shared__ __align__(16) unsigned short As[BM * LDA];

    const int t = threadIdx.x;
    const int row0 = blockIdx.x * BM;
    const int lane = t & 63;
    const int wave = t >> 6;
    const int wm = (wave & 1) * 32;
    const int wn = (wave >> 1) * 64;
    const int l15 = lane & 15;
    const int l4  = lane >> 4;

    const int m0 = t >> 3, kq = t & 7;
    const int m1 = m0 + 32;
    const float* arow0 = A + (size_t)(row0 + m0) * K;
    const float* arow1 = A + (size_t)(row0 + m1) * K;
    const bool rv0 = (row0 + m0) < N_NODES;
    const bool rv1 = (row0 + m1) < N_NODES;

    const f32x4 zero = {0.0f, 0.0f, 0.0f, 0.0f};
    f32x4 acc[2][4];
#pragma unroll
    for (int i = 0; i < 2; ++i)
#pragma unroll
        for (int j = 0; j < 4; ++j) acc[i][j] = zero;

    float4 pf0, pf1;
    auto ldA = [&](int k0, float4& d, const float* row, bool rowok) {
        int k = k0 + kq * 4;
        if (rowok && k < K) d = *reinterpret_cast<const float4*>(row + k);
        else d = make_float4(0.0f, 0.0f, 0.0f, 0.0f);
    };
    ldA(0, pf0, arow0, rv0);
    ldA(0, pf1, arow1, rv1);

    for (int s = 0; s < 16; ++s) {
        const int k0 = s * 32;
        __syncthreads();
        {
            unsigned short h[4];
            h[0] = f2bf(pf0.x); h[1] = f2bf(pf0.y);
            h[2] = f2bf(pf0.z); h[3] = f2bf(pf0.w);
            *reinterpret_cast<uint2*>(&As[m0 * LDA + kq * 4]) =
                *reinterpret_cast<uint2*>(h);
            h[0] = f2bf(pf1.x); h[1] = f2bf(pf1.y);
            h[2] = f2bf(pf1.z); h[3] = f2bf(pf1.w);
            *reinterpret_cast<uint2*>(&As[m1 * LDA + kq * 4]) =
                *reinterpret_cast<uint2*>(h);
        }
        __syncthreads();
        if (s < 15) {
            ldA(k0 + 32, pf0, arow0, rv0);
            ldA(k0 + 32, pf1, arow1, rv1);
        }

        bf16x8 af[2];
#pragma unroll
        for (int i = 0; i < 2; ++i) {
            int m = wm + i * 16 + l15;
            af[i] = *reinterpret_cast<const bf16x8*>(&As[m * LDA + l4 * 8]);
        }
        bf16x8 bfr[4];
#pragma unroll
        for (int j = 0; j < 4; ++j) {
            int n = wn + j * 16 + l15;
            bfr[j] = *reinterpret_cast<const bf16x8*>(
                Bt + (size_t)n * 512 + k0 + l4 * 8);
        }
#pragma unroll
        for (int i = 0; i < 2; ++i)
#pragma unroll
            for (int j = 0; j < 4; ++j)
                acc[i][j] = __builtin_amdgcn_mfma_f32_16x16x32_bf16(
                    af[i], bfr[j], acc[i][j], 0, 0, 0);
    }

#pragma unroll
    for (int i = 0; i < 2; ++i) {
#pragma unroll
        for (int r = 0; r < 4; ++r) {
            int row = row0 + wm + i * 16 + l4 * 4 + r;
            if (row < N_NODES) {
#pragma unroll
                for (int j = 0; j < 4; ++j) {
                    int col = wn + j * 16 + l15;
                    C[(size_t)row * N + col] = f2bf(acc[i][j][r]);
                }
            }
        }
    }
}

// ---------------------------------------------------------------------------
// Small-K GEMM: C[M,N] = f(A[M,K]) @ B[K,N] (+ bC), f = relu(a + bA[k]).
// OUT_BF16: emit bf16 (halves downstream random-gather traffic).
// ---------------------------------------------------------------------------
template <int K, int N, int TM, int TN, bool RELU_A, bool BIAS_C, bool OUT_BF16>
__global__ __launch_bounds__(256) void gemm_small_kernel(
    const float* __restrict__ A, const float* __restrict__ B,
    const float* __restrict__ bA, const float* __restrict__ bC,
    void* __restrict__ Cv, int M)
{
    constexpr int BM = 64;
    constexpr int BK = 32;
    constexpr int PAD = BM + 4;
    constexpr int RG = BM / TM;
    constexpr int CG = N / TN;
    static_assert(RG * CG == 256, "thread layout");
    static_assert(K % BK == 0, "K chunking");

    __shared__ float Bs[K * N];
    __shared__ float As[BK * PAD];

    const int t = threadIdx.x;
    const int row0 = blockIdx.x * BM;
    const int tx = t % CG;
    const int ty = t / CG;

    constexpr int BLOADS = (K * N) / 256;
#pragma unroll
    for (int i = 0; i < BLOADS; ++i) {
        int idx = t + i * 256;
        Bs[idx] = B[idx];
    }

    float acc[TM][TN] = {};

    for (int k0 = 0; k0 < K; k0 += BK) {
        float av[(BK * BM) / 256];
#pragma unroll
        for (int i = 0; i < (BK * BM) / 256; ++i) {
            int idx = t + i * 256;
            int kk = idx % BK, m = idx / BK;
            int gr = row0 + m;
            float v = (gr < M) ? A[(size_t)gr * K + k0 + kk] : 0.0f;
            if constexpr (RELU_A) {
                v += bA[k0 + kk];
                v = v > 0.0f ? v : 0.0f;
            }
            av[i] = v;
        }
        __syncthreads();
#pragma unroll
        for (int i = 0; i < (BK * BM) / 256; ++i) {
            int idx = t + i * 256;
            As[(idx % BK) * PAD + idx / BK] = av[i];
        }
        __syncthreads();
#pragma unroll
        for (int kk = 0; kk < BK; ++kk) {
            float a[TM], b[TN];
#pragma unroll
            for (int i = 0; i < TM; ++i) a[i] = As[kk * PAD + ty * TM + i];
#pragma unroll
            for (int j = 0; j < TN; ++j) b[j] = Bs[(k0 + kk) * N + tx * TN + j];
#pragma unroll
            for (int i = 0; i < TM; ++i)
#pragma unroll
                for (int j = 0; j < TN; ++j) acc[i][j] += a[i] * b[j];
        }
    }

#pragma unroll
    for (int i = 0; i < TM; ++i) {
        int gr = row0 + ty * TM + i;
        if (gr < M) {
            float v[TN];
#pragma unroll
            for (int j = 0; j < TN; ++j) {
                v[j] = acc[i][j];
                if constexpr (BIAS_C) v[j] += bC[tx * TN + j];
            }
            if constexpr (OUT_BF16) {
                unsigned short* C = (unsigned short*)Cv;
                if constexpr (TN == 4) {
                    unsigned short h[4] = {f2bf(v[0]), f2bf(v[1]), f2bf(v[2]), f2bf(v[3])};
                    *reinterpret_cast<uint2*>(C + (size_t)gr * N + tx * 4) =
                        *reinterpret_cast<uint2*>(h);
                } else {
#pragma unroll
                    for (int j = 0; j < TN; ++j)
                        C[(size_t)gr * N + tx * TN + j] = f2bf(v[j]);
                }
            } else {
                float* C = (float*)Cv;
                if constexpr (TN == 4) {
                    float4 q = {v[0], v[1], v[2], v[3]};
                    *reinterpret_cast<float4*>(C + (size_t)gr * N + tx * 4) = q;
                } else {
#pragma unroll
                    for (int j = 0; j < TN; ++j)
                        C[(size_t)gr * N + tx * TN + j] = v[j];
                }
            }
        }
    }
}

// ---------------------------------------------------------------------------
// CSR build (per launch; reused by all 3 aggregation layers).
// ---------------------------------------------------------------------------
__global__ __launch_bounds__(256) void hist_kernel(
    const int* __restrict__ src, int* __restrict__ counts)
{
    int e = blockIdx.x * 256 + threadIdx.x;
    if (e < N_EDGES) atomicAdd(&counts[src[e]], 1);
}

// Single-block coalesced tile scan: counts[0..N) -> row_ptr/cursor (exclusive).
// 13 tiles of 4096 (int4/thread, lane-contiguous = fully coalesced loads and
// stores). Per tile: wave shuffle scan + 16-wave LDS scan + running carry.
__global__ __launch_bounds__(1024) void scan_kernel(
    const int* __restrict__ counts, int* __restrict__ row_ptr,
    int* __restrict__ cursor)
{
    constexpr int Q = N_NODES / 4;   // 12500 int4 groups (N_NODES % 4 == 0)
    const int t = threadIdx.x;
    const int lane = t & 63, wave = t >> 6;
    __shared__ int wsum[16];
    __shared__ int carry_s;
    int carry = 0;
    const int4* c4 = reinterpret_cast<const int4*>(counts);
    int4* rp4 = reinterpret_cast<int4*>(row_ptr);
    int4* cu4 = reinterpret_cast<int4*>(cursor);

    for (int base = 0; base < Q; base += 1024) {
        const int g = base + t;
        int4 v = {0, 0, 0, 0};
        if (g < Q) v = c4[g];
        const int s = v.x + v.y + v.z + v.w;

        int incl = s;
#pragma unroll
        for (int off = 1; off < 64; off <<= 1) {
            int n = __shfl_up(incl, off, 64);
            if (lane >= off) incl += n;
        }
        if (lane == 63) wsum[wave] = incl;
        __syncthreads();
        if (t < 16) {
            int w = wsum[t];
            int inc = w;
#pragma unroll
            for (int off = 1; off < 16; off <<= 1) {
                int n = __shfl_up(inc, off, 64);
                if (t >= off) inc += n;
            }
            wsum[t] = inc - w;              // exclusive wave offset
            if (t == 15) carry_s = inc;     // tile total
        }
        __syncthreads();
        if (g < Q) {
            int e0 = carry + wsum[wave] + (incl - s);
            int4 r;
            r.x = e0;
            r.y = r.x + v.x;
            r.z = r.y + v.y;
            r.w = r.z + v.z;
            rp4[g] = r;
            cu4[g] = r;
        }
        carry += carry_s;
        __syncthreads();   // protect wsum/carry_s before next tile overwrites
    }
    if (t == 0) row_ptr[N_NODES] = carry;
}

__global__ __launch_bounds__(256) void fill_kernel(
    const int* __restrict__ src, const int* __restrict__ dst,
    const float* __restrict__ vals, int* __restrict__ cursor,
    int2* __restrict__ pairs)
{
    int e = blockIdx.x * 256 + threadIdx.x;
    if (e >= N_EDGES) return;
    int pos = atomicAdd(&cursor[src[e]], 1);
    pairs[pos] = make_int2(dst[e], __float_as_int(vals[e]));
}

// ---------------------------------------------------------------------------
// CSR gather, bf16 support (F=128): 16 lanes/node, 16 B (8 feats) per lane.
// ---------------------------------------------------------------------------
__global__ __launch_bounds__(256) void gather128_bf16_kernel(
    const unsigned short* __restrict__ support, const int2* __restrict__ pairs,
    const int* __restrict__ row_ptr, float* __restrict__ agg)
{
    const int node = blockIdx.x * 16 + (threadIdx.x >> 4);
    if (node >= N_NODES) return;
    const int lane = threadIdx.x & 15;
    int i = row_ptr[node];
    const int end = row_ptr[node + 1];

    float acc[8] = {};
    for (; i + 2 <= end; i += 2) {
        int2 p0 = pairs[i], p1 = pairs[i + 1];
        float v0 = __int_as_float(p0.y), v1 = __int_as_float(p1.y);
        uint4 r0 = *reinterpret_cast<const uint4*>(
            support + (size_t)p0.x * 128 + lane * 8);
        uint4 r1 = *reinterpret_cast<const uint4*>(
            support + (size_t)p1.x * 128 + lane * 8);
        unsigned w0[4] = {r0.x, r0.y, r0.z, r0.w};
        unsigned w1[4] = {r1.x, r1.y, r1.z, r1.w};
#pragma unroll
        for (int j = 0; j < 4; ++j) {
            acc[2 * j]     += __uint_as_float(w0[j] << 16) * v0;
            acc[2 * j + 1] += __uint_as_float(w0[j] & 0xffff0000u) * v0;
            acc[2 * j]     += __uint_as_float(w1[j] << 16) * v1;
            acc[2 * j + 1] += __uint_as_float(w1[j] & 0xffff0000u) * v1;
        }
    }
    if (i < end) {
        int2 p = pairs[i];
        float v = __int_as_float(p.y);
        uint4 r = *reinterpret_cast<const uint4*>(
            support + (size_t)p.x * 128 + lane * 8);
        unsigned w[4] = {r.x, r.y, r.z, r.w};
#pragma unroll
        for (int j = 0; j < 4; ++j) {
            acc[2 * j]     += __uint_as_float(w[j] << 16) * v;
            acc[2 * j + 1] += __uint_as_float(w[j] & 0xffff0000u) * v;
        }
    }
    float4 o0 = {acc[0], acc[1], acc[2], acc[3]};
    float4 o1 = {acc[4], acc[5], acc[6], acc[7]};
    float4* op = reinterpret_cast<float4*>(agg + (size_t)node * 128 + lane * 8);
    op[0] = o0; op[1] = o1;
}

// CSR gather, bf16 support (F=64): 8 lanes/node, 16 B (8 feats) per lane.
__global__ __launch_bounds__(256) void gather64_bf16_kernel(
    const unsigned short* __restrict__ support, const int2* __restrict__ pairs,
    const int* __restrict__ row_ptr, float* __restrict__ agg)
{
    const int node = blockIdx.x * 32 + (threadIdx.x >> 3);
    if (node >= N_NODES) return;
    const int lane = threadIdx.x & 7;
    int i = row_ptr[node];
    const int end = row_ptr[node + 1];

    float acc[8] = {};
    for (; i + 2 <= end; i += 2) {
        int2 p0 = pairs[i], p1 = pairs[i + 1];
        float v0 = __int_as_float(p0.y), v1 = __int_as_float(p1.y);
        uint4 r0 = *reinterpret_cast<const uint4*>(
            support + (size_t)p0.x * 64 + lane * 8);
        uint4 r1 = *reinterpret_cast<const uint4*>(
            support + (size_t)p1.x * 64 + lane * 8);
        unsigned w0[4] = {r0.x, r0.y, r0.z, r0.w};
        unsigned w1[4] = {r1.x, r1.y, r1.z, r1.w};
#pragma unroll
        for (int j = 0; j < 4; ++j) {
            acc[2 * j]     += __uint_as_float(w0[j] << 16) * v0;
            acc[2 * j + 1] += __uint_as_float(w0[j] & 0xffff0000u) * v0;
            acc[2 * j]     += __uint_as_float(w1[j] << 16) * v1;
            acc[2 * j + 1] += __uint_as_float(w1[j] & 0xffff0000u) * v1;
        }
    }
    if (i < end) {
        int2 p = pairs[i];
        float v = __int_as_float(p.y);
        uint4 r = *reinterpret_cast<const uint4*>(
            support + (size_t)p.x * 64 + lane * 8);
        unsigned w[4] = {r.x, r.y, r.z, r.w};
#pragma unroll
        for (int j = 0; j < 4; ++j) {
            acc[2 * j]     += __uint_as_float(w[j] << 16) * v;
            acc[2 * j + 1] += __uint_as_float(w[j] & 0xffff0000u) * v;
        }
    }
    float4 o0 = {acc[0], acc[1], acc[2], acc[3]};
    float4 o1 = {acc[4], acc[5], acc[6], acc[7]};
    float4* op = reinterpret_cast<float4*>(agg + (size_t)node * 64 + lane * 8);
    op[0] = o0; op[1] = o1;
}

// fp32 gather for F = 16 (support3 remains fp32).
template <int F>
__global__ __launch_bounds__(256) void gather_kernel(
    const float* __restrict__ support, const int2* __restrict__ pairs,
    const int* __restrict__ row_ptr, float* __restrict__ agg)
{
    constexpr int TPN = F / 4;
    constexpr int NPB = 256 / TPN;
    const int node = blockIdx.x * NPB + threadIdx.x / TPN;
    if (node >= N_NODES) return;
    const int lane = threadIdx.x % TPN;
    int i = row_ptr[node];
    const int end = row_ptr[node + 1];

    float4 acc0 = {0, 0, 0, 0};
    float4 acc1 = {0, 0, 0, 0};

    for (; i + 2 <= end; i += 2) {
        int2 p0 = pairs[i];
        int2 p1 = pairs[i + 1];
        float v0 = __int_as_float(p0.y);
        float v1 = __int_as_float(p1.y);
        const float4 m0 = *reinterpret_cast<const float4*>(
            support + (size_t)p0.x * F + lane * 4);
        const float4 m1 = *reinterpret_cast<const float4*>(
            support + (size_t)p1.x * F + lane * 4);
        acc0.x += m0.x * v0; acc0.y += m0.y * v0;
        acc0.z += m0.z * v0; acc0.w += m0.w * v0;
        acc1.x += m1.x * v1; acc1.y += m1.y * v1;
        acc1.z += m1.z * v1; acc1.w += m1.w * v1;
    }
    if (i < end) {
        int2 p = pairs[i];
        float v = __int_as_float(p.y);
        const float4 m = *reinterpret_cast<const float4*>(
            support + (size_t)p.x * F + lane * 4);
        acc0.x += m.x * v; acc0.y += m.y * v;
        acc0.z += m.z * v; acc0.w += m.w * v;
    }
    acc0.x += acc1.x; acc0.y += acc1.y; acc0.z += acc1.z; acc0.w += acc1.w;
    *reinterpret_cast<float4*>(agg + (size_t)node * F + lane * 4) = acc0;
}

// ---------------------------------------------------------------------------
// Row-wise log_softmax over 16 columns (with bias b3).
// ---------------------------------------------------------------------------
__global__ __launch_bounds__(256) void logsoftmax_kernel(
    const float* __restrict__ agg, const float* __restrict__ b3,
    float* __restrict__ out)
{
    int row = blockIdx.x * 256 + threadIdx.x;
    if (row >= N_NODES) return;
    float v[16];
    const float4* p = reinterpret_cast<const float4*>(agg + (size_t)row * 16);
#pragma unroll
    for (int i = 0; i < 4; ++i) {
        float4 q = p[i];
        v[i * 4 + 0] = q.x + b3[i * 4 + 0];
        v[i * 4 + 1] = q.y + b3[i * 4 + 1];
        v[i * 4 + 2] = q.z + b3[i * 4 + 2];
        v[i * 4 + 3] = q.w + b3[i * 4 + 3];
    }
    float mx = v[0];
#pragma unroll
    for (int i = 1; i < 16; ++i) mx = fmaxf(mx, v[i]);
    float s = 0.0f;
#pragma unroll
    for (int i = 0; i < 16; ++i) s += expf(v[i] - mx);
    float lse = mx + logf(s);
    float4* o = reinterpret_cast<float4*>(out + (size_t)row * 16);
#pragma unroll
    for (int i = 0; i < 4; ++i)
        o[i] = make_float4(v[i * 4 + 0] - lse, v[i * 4 + 1] - lse,
                           v[i * 4 + 2] - lse, v[i * 4 + 3] - lse);
}

// ---------------------------------------------------------------------------
extern "C" void kernel_launch(void* const* d_in, const int* in_sizes, int n_in,
                              void* d_out, int out_size, void* d_ws, size_t ws_size,
                              hipStream_t stream)
{
    const float* x         = (const float*)d_in[0];
    const float* edge_vals = (const float*)d_in[1];
    const float* W1 = (const float*)d_in[2];
    const float* b1 = (const float*)d_in[3];
    const float* W2 = (const float*)d_in[4];
    const float* b2 = (const float*)d_in[5];
    const float* W3 = (const float*)d_in[6];
    const float* b3 = (const float*)d_in[7];
    const float* We = (const float*)d_in[8];
    const float* be = (const float*)d_in[9];
    const int* esrc = (const int*)d_in[10];
    const int* edst = (const int*)d_in[11];

    float* out1 = (float*)d_out;                        // [50000,16]
    float* out2 = (float*)d_out + (size_t)N_NODES * 16; // [50000,64]

    char* ws = (char*)d_ws;
    float* bufA    = (float*)(ws);                    // 25,600,000
    float* bufB    = (float*)(ws + 25600000);         // 25,600,000
    float* bufC    = (float*)(ws + 51200000);         //  3,200,000
    int*   counts  = (int*)  (ws + 54400000);         //    200,064
    int*   row_ptr = (int*)  (ws + 54600064);         //    200,064
    int*   cursor  = (int*)  (ws + 54800128);         //    200,064
    int2*  pairs   = (int2*) (ws + 55000192);         //  6,400,000
    // total: 61,400,192 B

    unsigned short* W1bf   = (unsigned short*)bufC;   // 131 KB, free until step 7
    unsigned short* sup1bf = (unsigned short*)bufA;   // [N,128] bf16
    unsigned short* sup2bf = (unsigned short*)bufA;   // [N,64] bf16 (reuses bufA)

    const int MB = (N_NODES + 63) / 64;   // 782
    const int EB = (N_EDGES + 255) / 256; // 3125

    // --- one-time weight prep + CSR build ---
    convert_w1_kernel<<<256, 256, 0, stream>>>(W1, W1bf);
    hipMemsetAsync(counts, 0, (size_t)N_NODES * 4, stream);
    hist_kernel<<<EB, 256, 0, stream>>>(esrc, counts);
    scan_kernel<<<1, 1024, 0, stream>>>(counts, row_ptr, cursor);
    fill_kernel<<<EB, 256, 0, stream>>>(esrc, edst, edge_vals, cursor, pairs);

    // 1. support1 = x @ W1 (bf16 MFMA)              -> bufA [N,128] bf16
    gemm1_mfma_kernel<<<MB, 256, 0, stream>>>(x, W1bf, sup1bf);

    // 2. agg1 = CSR-gather(support1 bf16)           -> bufB [N,128] fp32
    gather128_bf16_kernel<<<(N_NODES + 15) / 16, 256, 0, stream>>>(
        sup1bf, pairs, row_ptr, bufB);

    // 3. support2 = relu(agg1 + b1) @ W2            -> bufA [N,64] bf16
    gemm_small_kernel<128, 64, 4, 4, true, false, true><<<MB, 256, 0, stream>>>(
        bufB, W2, b1, nullptr, (void*)sup2bf, N_NODES);

    // 4. agg2 = CSR-gather(support2 bf16)           -> bufB [N,64] fp32
    gather64_bf16_kernel<<<(N_NODES + 31) / 32, 256, 0, stream>>>(
        sup2bf, pairs, row_ptr, bufB);

    // 5. out2 = relu(agg2 + b2) @ We + be           -> d_out tail (fp32)
    gemm_small_kernel<64, 64, 4, 4, true, true, false><<<MB, 256, 0, stream>>>(
        bufB, We, b2, be, (void*)out2, N_NODES);

    // 6. support3 = relu(agg2 + b2) @ W3            -> bufA [N,16] fp32
    gemm_small_kernel<64, 16, 4, 1, true, false, false><<<MB, 256, 0, stream>>>(
        bufB, W3, b2, nullptr, (void*)bufA, N_NODES);

    // 7. agg3 = CSR-gather(support3)                -> bufC [N,16] (over W1bf, done)
    gather_kernel<16><<<(N_NODES * 4 + 255) / 256, 256, 0, stream>>>(
        bufA, pairs, row_ptr, bufC);

    // 8. out1 = log_softmax(agg3 + b3)              -> d_out head
    logsoftmax_kernel<<<(N_NODES + 255) / 256, 256, 0, stream>>>(bufC, b3, out1);
}